// Round 7
// baseline (334.867 us; speedup 1.0000x reference)
//
#include <hip/hip_runtime.h>
#include <hip/hip_bf16.h>

// MultiheadAttention: B=2, S=2048, D=1024, H=16, dk=64.
// Inputs fp32, output fp32. Internals bf16 MFMA.
// V is produced TRANSPOSED ([feature][token]) by its projection GEMM so the
// attention kernel stages both K and V^T with coalesced uint4 loads.

typedef __attribute__((ext_vector_type(8))) short short8;   // 8 bf16 = 4 VGPR (MFMA A/B frag)
typedef __attribute__((ext_vector_type(4))) float floatx4;  // MFMA C/D frag

#define D_MODEL 1024
#define SEQ 2048
#define NTOK 4096      // B*S
#define DK 64
#define NH 16
#define MAT 4194304    // NTOK*D_MODEL
#define WMAT 1048576   // D_MODEL*D_MODEL

static __device__ __forceinline__ unsigned short f2bf(float f) {
    unsigned int x = __float_as_uint(f);
    unsigned int r = x + 0x7fffu + ((x >> 16) & 1u);   // RNE
    return (unsigned short)(r >> 16);
}
static __device__ __forceinline__ float bf2f(unsigned short u) {
    return __uint_as_float(((unsigned int)u) << 16);
}
static __device__ __forceinline__ unsigned pk2(float x, float y) {
    __hip_bfloat162 h = __float22bfloat162_rn(make_float2(x, y));
    return *reinterpret_cast<unsigned*>(&h);
}
static __device__ __forceinline__ short8 cvt8(float4 f0, float4 f1) {
    union { unsigned u[4]; short8 s; } r;
    r.u[0] = pk2(f0.x, f0.y); r.u[1] = pk2(f0.z, f0.w);
    r.u[2] = pk2(f1.x, f1.y); r.u[3] = pk2(f1.z, f1.w);
    return r.s;
}

// ---------------------------------------------------------------------------
// fp32 -> bf16 conversion pass: xq,xk,xv (4M each) + wq,wk,wv,wo (1M each)
// ---------------------------------------------------------------------------
__global__ __launch_bounds__(256) void cvt7(
    const float* __restrict__ s0, const float* __restrict__ s1,
    const float* __restrict__ s2, const float* __restrict__ s3,
    const float* __restrict__ s4, const float* __restrict__ s5,
    const float* __restrict__ s6, unsigned short* __restrict__ dst) {
    const float* s; size_t doff; int n;
    switch (blockIdx.y) {
        case 0: s = s0; doff = 0;                          n = MAT;  break;
        case 1: s = s1; doff = (size_t)MAT;                n = MAT;  break;
        case 2: s = s2; doff = (size_t)2 * MAT;            n = MAT;  break;
        case 3: s = s3; doff = (size_t)3 * MAT;            n = WMAT; break;
        case 4: s = s4; doff = (size_t)3 * MAT + WMAT;     n = WMAT; break;
        case 5: s = s5; doff = (size_t)3 * MAT + 2 * WMAT; n = WMAT; break;
        default: s = s6; doff = (size_t)3 * MAT + 3 * WMAT; n = WMAT; break;
    }
    int idx = (blockIdx.x * 256 + threadIdx.x) * 8;
    if (idx >= n) return;
    float4 a = *(const float4*)(s + idx);
    float4 b = *(const float4*)(s + idx + 4);
    *(short8*)&dst[doff + idx] = cvt8(a, b);
}

// ---------------------------------------------------------------------------
// 128x128 NT GEMM, bf16 operands: out[m,n] = sum_k X[m,k]*W[n,k] + bias
// ROWBIAS: bias indexed by m (for transposed-output GEMMs). OSTRIDE: out row
// stride in elements.
// ---------------------------------------------------------------------------
template <bool F32OUT, bool ROWBIAS, int OSTRIDE>
static __device__ __forceinline__ void gemm_bb(const unsigned short* __restrict__ X,
                                               const unsigned short* __restrict__ W,
                                               const float* __restrict__ bias,
                                               void* __restrict__ outp) {
    __shared__ __align__(16) unsigned short Asm[128 * 72];
    __shared__ __align__(16) unsigned short Bsm[128 * 72];

    const int tid = threadIdx.x;
    const int lane = tid & 63;
    const int wv = tid >> 6;
    const int g = lane >> 4;
    const int lm = lane & 15;
    const int wr = wv >> 1;
    const int wc = wv & 1;
    const int m0 = blockIdx.y * 128;
    const int n0 = blockIdx.x * 128;

    floatx4 acc[4][4];
#pragma unroll
    for (int mi = 0; mi < 4; ++mi)
#pragma unroll
        for (int ni = 0; ni < 4; ++ni)
            acc[mi][ni] = (floatx4){0.f, 0.f, 0.f, 0.f};

    for (int k0 = 0; k0 < 1024; k0 += 64) {
#pragma unroll
        for (int i = 0; i < 4; ++i) {
            int idx = tid + i * 256;
            int row = idx >> 3;
            int col = (idx & 7) << 3;
            *(uint4*)&Asm[row * 72 + col] =
                *(const uint4*)&X[(size_t)(m0 + row) * 1024 + k0 + col];
            *(uint4*)&Bsm[row * 72 + col] =
                *(const uint4*)&W[(size_t)(n0 + row) * 1024 + k0 + col];
        }
        __syncthreads();
#pragma unroll
        for (int ks = 0; ks < 64; ks += 32) {
            short8 af[4], bfr[4];
#pragma unroll
            for (int mi = 0; mi < 4; ++mi)
                af[mi] = *(const short8*)&Asm[(wr * 64 + mi * 16 + lm) * 72 + ks + g * 8];
#pragma unroll
            for (int ni = 0; ni < 4; ++ni)
                bfr[ni] = *(const short8*)&Bsm[(wc * 64 + ni * 16 + lm) * 72 + ks + g * 8];
#pragma unroll
            for (int mi = 0; mi < 4; ++mi)
#pragma unroll
                for (int ni = 0; ni < 4; ++ni)
                    acc[mi][ni] = __builtin_amdgcn_mfma_f32_16x16x32_bf16(
                        af[mi], bfr[ni], acc[mi][ni], 0, 0, 0);
        }
        __syncthreads();
    }

    float cb[4];
#pragma unroll
    for (int ni = 0; ni < 4; ++ni)
        cb[ni] = ROWBIAS ? 0.f : bias[n0 + wc * 64 + ni * 16 + lm];
#pragma unroll
    for (int mi = 0; mi < 4; ++mi)
#pragma unroll
        for (int r = 0; r < 4; ++r) {
            int rowg = m0 + wr * 64 + mi * 16 + g * 4 + r;
            float rb = ROWBIAS ? bias[rowg] : 0.f;
#pragma unroll
            for (int ni = 0; ni < 4; ++ni) {
                int colg = n0 + wc * 64 + ni * 16 + lm;
                float val = acc[mi][ni][r] + (ROWBIAS ? rb : cb[ni]);
                if (F32OUT)
                    ((float*)outp)[(size_t)rowg * OSTRIDE + colg] = val;
                else
                    ((unsigned short*)outp)[(size_t)rowg * OSTRIDE + colg] = f2bf(val);
            }
        }
}

__global__ __launch_bounds__(256) void qkv_gemm_b(
    const unsigned short* __restrict__ Xb, const unsigned short* __restrict__ Wb,
    const float* __restrict__ bq, const float* __restrict__ bk,
    unsigned short* __restrict__ QK) {
    const int z = blockIdx.z;                    // 0 = Q, 1 = K
    const float* bias = (z == 0) ? bq : bk;
    gemm_bb<false, false, 1024>(Xb + (size_t)z * MAT, Wb + (size_t)z * WMAT, bias,
                                QK + (size_t)z * MAT);
}

// V^T projection: out[m=feature][n=token] = sum_k Wv[m,k]*Xv[n,k] + bv[m]
__global__ __launch_bounds__(256) void vt_gemm_b(
    const unsigned short* __restrict__ Wv, const unsigned short* __restrict__ Xv,
    const float* __restrict__ bv, unsigned short* __restrict__ VT) {
    gemm_bb<false, true, 4096>(Wv, Xv, bv, VT);
}

__global__ __launch_bounds__(256) void out_gemm_b(
    const unsigned short* __restrict__ ctx, const unsigned short* __restrict__ Wo,
    const float* __restrict__ bo, float* __restrict__ out) {
    gemm_bb<true, false, 1024>(ctx, Wo, bo, out);
}

// ---------------- fallback path (fp32 staging), used if ws too small --------
template <bool ROWBIAS, int OSTRIDE>
static __device__ __forceinline__ void gemm128_f(const float* __restrict__ X,
                                                 const float* __restrict__ W,
                                                 const float* __restrict__ bias,
                                                 unsigned short* __restrict__ out) {
    __shared__ __align__(16) unsigned short Asm[128 * 72];
    __shared__ __align__(16) unsigned short Bsm[128 * 72];
    const int tid = threadIdx.x;
    const int lane = tid & 63;
    const int wv = tid >> 6;
    const int g = lane >> 4;
    const int lm = lane & 15;
    const int wr = wv >> 1;
    const int wc = wv & 1;
    const int m0 = blockIdx.y * 128;
    const int n0 = blockIdx.x * 128;
    floatx4 acc[4][4];
#pragma unroll
    for (int mi = 0; mi < 4; ++mi)
#pragma unroll
        for (int ni = 0; ni < 4; ++ni)
            acc[mi][ni] = (floatx4){0.f, 0.f, 0.f, 0.f};
    for (int k0 = 0; k0 < 1024; k0 += 64) {
#pragma unroll
        for (int i = 0; i < 4; ++i) {
            int idx = tid + i * 256;
            int row = idx >> 3;
            int col = (idx & 7) << 3;
            const float* sa = &X[(size_t)(m0 + row) * 1024 + k0 + col];
            *(short8*)&Asm[row * 72 + col] = cvt8(*(const float4*)sa, *(const float4*)(sa + 4));
            const float* sb = &W[(size_t)(n0 + row) * 1024 + k0 + col];
            *(short8*)&Bsm[row * 72 + col] = cvt8(*(const float4*)sb, *(const float4*)(sb + 4));
        }
        __syncthreads();
#pragma unroll
        for (int ks = 0; ks < 64; ks += 32) {
            short8 af[4], bfr[4];
#pragma unroll
            for (int mi = 0; mi < 4; ++mi)
                af[mi] = *(const short8*)&Asm[(wr * 64 + mi * 16 + lm) * 72 + ks + g * 8];
#pragma unroll
            for (int ni = 0; ni < 4; ++ni)
                bfr[ni] = *(const short8*)&Bsm[(wc * 64 + ni * 16 + lm) * 72 + ks + g * 8];
#pragma unroll
            for (int mi = 0; mi < 4; ++mi)
#pragma unroll
                for (int ni = 0; ni < 4; ++ni)
                    acc[mi][ni] = __builtin_amdgcn_mfma_f32_16x16x32_bf16(
                        af[mi], bfr[ni], acc[mi][ni], 0, 0, 0);
        }
        __syncthreads();
    }
    float cb[4];
#pragma unroll
    for (int ni = 0; ni < 4; ++ni)
        cb[ni] = ROWBIAS ? 0.f : bias[n0 + wc * 64 + ni * 16 + lm];
#pragma unroll
    for (int mi = 0; mi < 4; ++mi)
#pragma unroll
        for (int r = 0; r < 4; ++r) {
            int rowg = m0 + wr * 64 + mi * 16 + g * 4 + r;
            float rb = ROWBIAS ? bias[rowg] : 0.f;
#pragma unroll
            for (int ni = 0; ni < 4; ++ni) {
                int colg = n0 + wc * 64 + ni * 16 + lm;
                out[(size_t)rowg * OSTRIDE + colg] =
                    f2bf(acc[mi][ni][r] + (ROWBIAS ? rb : cb[ni]));
            }
        }
}

__global__ __launch_bounds__(256) void qkv_gemm_f(
    const float* __restrict__ xq, const float* __restrict__ xk,
    const float* __restrict__ wq, const float* __restrict__ wk,
    const float* __restrict__ bq, const float* __restrict__ bk,
    unsigned short* __restrict__ q, unsigned short* __restrict__ k) {
    if (blockIdx.z == 0) gemm128_f<false, 1024>(xq, wq, bq, q);
    else                 gemm128_f<false, 1024>(xk, wk, bk, k);
}

__global__ __launch_bounds__(256) void vt_gemm_f(
    const float* __restrict__ wv, const float* __restrict__ xv,
    const float* __restrict__ bv, unsigned short* __restrict__ VT) {
    gemm128_f<true, 4096>(wv, xv, bv, VT);
}

__global__ __launch_bounds__(256) void out_gemm_f(
    const float* __restrict__ wo, const float* __restrict__ bo,
    const unsigned short* __restrict__ ctx, float* __restrict__ out) {
    __shared__ __align__(16) unsigned short Asm[128 * 72];
    __shared__ __align__(16) unsigned short Bsm[128 * 72];
    const int tid = threadIdx.x;
    const int lane = tid & 63;
    const int wv = tid >> 6;
    const int g = lane >> 4;
    const int lm = lane & 15;
    const int wr = wv >> 1;
    const int wc = wv & 1;
    const int m0 = blockIdx.y * 128;
    const int n0 = blockIdx.x * 128;
    floatx4 acc[4][4];
#pragma unroll
    for (int mi = 0; mi < 4; ++mi)
#pragma unroll
        for (int ni = 0; ni < 4; ++ni)
            acc[mi][ni] = (floatx4){0.f, 0.f, 0.f, 0.f};
    for (int k0 = 0; k0 < 1024; k0 += 64) {
#pragma unroll
        for (int i = 0; i < 4; ++i) {
            int idx = tid + i * 256;
            int row = idx >> 3;
            int col = (idx & 7) << 3;
            *(uint4*)&Asm[row * 72 + col] =
                *(const uint4*)&ctx[(size_t)(m0 + row) * 1024 + k0 + col];
            const float* sb = &wo[(size_t)(n0 + row) * 1024 + k0 + col];
            *(short8*)&Bsm[row * 72 + col] = cvt8(*(const float4*)sb, *(const float4*)(sb + 4));
        }
        __syncthreads();
#pragma unroll
        for (int ks = 0; ks < 64; ks += 32) {
            short8 af[4], bfr[4];
#pragma unroll
            for (int mi = 0; mi < 4; ++mi)
                af[mi] = *(const short8*)&Asm[(wr * 64 + mi * 16 + lm) * 72 + ks + g * 8];
#pragma unroll
            for (int ni = 0; ni < 4; ++ni)
                bfr[ni] = *(const short8*)&Bsm[(wc * 64 + ni * 16 + lm) * 72 + ks + g * 8];
#pragma unroll
            for (int mi = 0; mi < 4; ++mi)
#pragma unroll
                for (int ni = 0; ni < 4; ++ni)
                    acc[mi][ni] = __builtin_amdgcn_mfma_f32_16x16x32_bf16(
                        af[mi], bfr[ni], acc[mi][ni], 0, 0, 0);
        }
        __syncthreads();
    }
    float bb[4];
#pragma unroll
    for (int ni = 0; ni < 4; ++ni)
        bb[ni] = bo[n0 + wc * 64 + ni * 16 + lm];
#pragma unroll
    for (int mi = 0; mi < 4; ++mi)
#pragma unroll
        for (int ni = 0; ni < 4; ++ni)
#pragma unroll
            for (int r = 0; r < 4; ++r) {
                int rowg = m0 + wr * 64 + mi * 16 + g * 4 + r;
                int colg = n0 + wc * 64 + ni * 16 + lm;
                out[(size_t)rowg * 1024 + colg] = acc[mi][ni][r] + bb[ni];
            }
}

// ---------------------------------------------------------------------------
// Flash attention v4: S^T orientation, P in registers, V pre-transposed.
//   Stage K[key][dk] and Vt[dk][key] tiles with coalesced uint4 loads
//   (software-pipelined: next tile's globals load during current MFMA work).
//   S^T = mfma(K_frag, Q_frag): C rows = keys kb*16+g*4+r, cols = q lm.
//   PV slot-remap (slot g*8+j <-> key c*16+g*4+(j&3), c=2cp+(j>>2)):
//     A = pk2-packed exp(S^T) from registers, B = Vt via 2x ds_read_b64.
// ---------------------------------------------------------------------------
__global__ __launch_bounds__(256) void attn_kernel(
    const unsigned short* __restrict__ Q, const unsigned short* __restrict__ K,
    const unsigned short* __restrict__ VT, unsigned short* __restrict__ CTX) {
    __shared__ __align__(16) unsigned short Ksm[64 * 72];
    __shared__ __align__(16) unsigned short Vt[64 * 72];

    const int tid = threadIdx.x;
    const int lane = tid & 63;
    const int w = tid >> 6;
    const int g = lane >> 4;
    const int lm = lane & 15;
    const int qt = blockIdx.x;
    const int bh = blockIdx.y;
    const int b = bh >> 4;
    const int h = bh & 15;

    const size_t base = (size_t)b * SEQ * D_MODEL + (size_t)h * DK;
    // VT: [1024 features][4096 tokens]; this head's rows h*64.., this batch's cols b*2048..
    const size_t vtbase = (size_t)(h * 64) * NTOK + (size_t)b * SEQ;

    // staging coords (shared by K and Vt tiles)
    const int srow0 = tid >> 3;            // 0..31   (+32 on second iter)
    const int scol = (tid & 7) << 3;       // 0,8,...,56

    // Q fragments (B-operand for S^T), prescaled by 1/8
    short8 qf[2];
    const int qrow = qt * 64 + w * 16 + lm;
#pragma unroll
    for (int t = 0; t < 2; ++t) {
        short8 raw = *(const short8*)&Q[base + (size_t)qrow * D_MODEL + t * 32 + g * 8];
        union { unsigned u[4]; short8 s; } r;
#pragma unroll
        for (int j = 0; j < 4; ++j) {
            float lo = bf2f((unsigned short)raw[2 * j]) * 0.125f;
            float hi = bf2f((unsigned short)raw[2 * j + 1]) * 0.125f;
            r.u[j] = pk2(lo, hi);
        }
        qf[t] = r.s;
    }

    float lsum = 0.f;
    floatx4 Oacc[4];
#pragma unroll
    for (int nb = 0; nb < 4; ++nb) Oacc[nb] = (floatx4){0.f, 0.f, 0.f, 0.f};

    // prefetch tile 0
    uint4 kpre[2], vpre[2];
#pragma unroll
    for (int i = 0; i < 2; ++i) {
        int row = srow0 + i * 32;
        kpre[i] = *(const uint4*)&K[base + (size_t)row * D_MODEL + scol];
        vpre[i] = *(const uint4*)&VT[vtbase + (size_t)row * NTOK + scol];
    }

    for (int kt = 0; kt < SEQ / 64; ++kt) {
        // ---- commit prefetched tile to LDS ----
#pragma unroll
        for (int i = 0; i < 2; ++i) {
            int row = srow0 + i * 32;
            *(uint4*)&Ksm[row * 72 + scol] = kpre[i];
            *(uint4*)&Vt[row * 72 + scol] = vpre[i];
        }
        __syncthreads();

        // ---- prefetch next tile (latency hidden behind MFMA below) ----
        if (kt + 1 < SEQ / 64) {
            const int krow1 = (kt + 1) * 64;
#pragma unroll
            for (int i = 0; i < 2; ++i) {
                int row = srow0 + i * 32;
                kpre[i] = *(const uint4*)&K[base + (size_t)(krow1 + row) * D_MODEL + scol];
                vpre[i] = *(const uint4*)&VT[vtbase + (size_t)row * NTOK + krow1 + scol];
            }
        }

        // ---- S^T = K Q^T / 8 : per kb, rows = keys kb*16+g*4+r, col q=lm ----
        float p[4][4];
#pragma unroll
        for (int kb = 0; kb < 4; ++kb) {
            floatx4 a = (floatx4){0.f, 0.f, 0.f, 0.f};
#pragma unroll
            for (int t = 0; t < 2; ++t) {
                short8 ak = *(const short8*)&Ksm[(kb * 16 + lm) * 72 + t * 32 + g * 8];
                a = __builtin_amdgcn_mfma_f32_16x16x32_bf16(ak, qf[t], a, 0, 0, 0);
            }
#pragma unroll
            for (int r = 0; r < 4; ++r) p[kb][r] = __expf(a[r]);
            lsum += (p[kb][0] + p[kb][1]) + (p[kb][2] + p[kb][3]);
        }

        // ---- O += P V  (slot g*8+j <-> key c*16+g*4+(j&3), c = 2cp+(j>>2)) ----
#pragma unroll
        for (int cp = 0; cp < 2; ++cp) {
            const int c0 = 2 * cp, c1 = 2 * cp + 1;
            union { unsigned u[4]; short8 s; } ap;
            ap.u[0] = pk2(p[c0][0], p[c0][1]);
            ap.u[1] = pk2(p[c0][2], p[c0][3]);
            ap.u[2] = pk2(p[c1][0], p[c1][1]);
            ap.u[3] = pk2(p[c1][2], p[c1][3]);
#pragma unroll
            for (int nb = 0; nb < 4; ++nb) {
                const int d = nb * 16 + lm;
                uint2 x0 = *(const uint2*)&Vt[d * 72 + c0 * 16 + g * 4];
                uint2 x1 = *(const uint2*)&Vt[d * 72 + c1 * 16 + g * 4];
                union { unsigned u[4]; short8 s; } bv;
                bv.u[0] = x0.x; bv.u[1] = x0.y; bv.u[2] = x1.x; bv.u[3] = x1.y;
                Oacc[nb] = __builtin_amdgcn_mfma_f32_16x16x32_bf16(
                    ap.s, bv.s, Oacc[nb], 0, 0, 0);
            }
        }
        __syncthreads();
    }

    // ---- softmax denominator: reduce over g, redistribute to rows ----
    lsum += __shfl_xor(lsum, 16, 64);
    lsum += __shfl_xor(lsum, 32, 64);   // all lanes: full l for q = w*16+lm
    float lr[4];
#pragma unroll
    for (int r = 0; r < 4; ++r)
        lr[r] = __shfl(lsum, g * 4 + r, 64);   // l for q-row = w*16+g*4+r

#pragma unroll
    for (int nb = 0; nb < 4; ++nb) {
#pragma unroll
        for (int r = 0; r < 4; ++r) {
            float val = Oacc[nb][r] / lr[r];
            int srow = qt * 64 + w * 16 + g * 4 + r;
            CTX[base + (size_t)srow * D_MODEL + nb * 16 + lm] = f2bf(val);
        }
    }
}

extern "C" void kernel_launch(void* const* d_in, const int* in_sizes, int n_in,
                              void* d_out, int out_size, void* d_ws, size_t ws_size,
                              hipStream_t stream) {
    const float* xq = (const float*)d_in[0];
    const float* xk = (const float*)d_in[1];
    const float* xv = (const float*)d_in[2];
    const float* wq = (const float*)d_in[3];
    const float* bq = (const float*)d_in[4];
    const float* wk = (const float*)d_in[5];
    const float* bk = (const float*)d_in[6];
    const float* wv = (const float*)d_in[7];
    const float* bv = (const float*)d_in[8];
    const float* wo = (const float*)d_in[9];
    const float* bo = (const float*)d_in[10];
    float* out = (float*)d_out;

    unsigned short* ws = (unsigned short*)d_ws;

    if (ws_size >= (size_t)68 * 1024 * 1024) {
        // bf16 path: Xb[3*MAT] | Wb[4*WMAT] | Q | K | VT | C
        unsigned short* Xb = ws;
        unsigned short* Wb = ws + (size_t)3 * MAT;
        unsigned short* Qw = Wb + (size_t)4 * WMAT;
        unsigned short* Kw = Qw + (size_t)MAT;
        unsigned short* VTw = Kw + (size_t)MAT;
        unsigned short* Cw = VTw + (size_t)MAT;

        cvt7<<<dim3(2048, 7), 256, 0, stream>>>(xq, xk, xv, wq, wk, wv, wo, ws);
        qkv_gemm_b<<<dim3(8, 32, 2), 256, 0, stream>>>(Xb, Wb, bq, bk, Qw);
        vt_gemm_b<<<dim3(32, 8), 256, 0, stream>>>(
            Wb + (size_t)2 * WMAT, Xb + (size_t)2 * MAT, bv, VTw);
        attn_kernel<<<dim3(SEQ / 64, 2 * NH), 256, 0, stream>>>(Qw, Kw, VTw, Cw);
        out_gemm_b<<<dim3(8, 32), 256, 0, stream>>>(Cw, Wb + (size_t)3 * WMAT, bo, out);
    } else {
        unsigned short* Qw = ws;
        unsigned short* Kw = ws + (size_t)MAT;
        unsigned short* VTw = ws + (size_t)2 * MAT;
        unsigned short* Cw = ws + (size_t)3 * MAT;
        qkv_gemm_f<<<dim3(8, 32, 2), 256, 0, stream>>>(xq, xk, wq, wk, bq, bk, Qw, Kw);
        vt_gemm_f<<<dim3(32, 8), 256, 0, stream>>>(wv, xv, bv, VTw);
        attn_kernel<<<dim3(SEQ / 64, 2 * NH), 256, 0, stream>>>(Qw, Kw, VTw, Cw);
        out_gemm_f<<<dim3(8, 32), 256, 0, stream>>>(wo, bo, Cw, out);
    }
}

// Round 8
// 265.139 us; speedup vs baseline: 1.2630x; 1.2630x over previous
//
#include <hip/hip_runtime.h>
#include <hip/hip_bf16.h>

// MultiheadAttention: B=2, S=2048, D=1024, H=16, dk=64.
// Inputs fp32, output fp32. Internals bf16 MFMA.
// V is produced TRANSPOSED ([feature][token]) by its projection GEMM so the
// attention kernel stages both K and V^T with coalesced uint4 loads and does
// NO transpose work in its inner loop. P stays in registers (S^T orientation).

typedef __attribute__((ext_vector_type(8))) short short8;   // 8 bf16 = 4 VGPR (MFMA A/B frag)
typedef __attribute__((ext_vector_type(4))) float floatx4;  // MFMA C/D frag

#define D_MODEL 1024
#define SEQ 2048
#define NTOK 4096      // B*S
#define DK 64
#define NH 16
#define MAT 4194304    // NTOK*D_MODEL
#define WMAT 1048576   // D_MODEL*D_MODEL

static __device__ __forceinline__ unsigned short f2bf(float f) {
    unsigned int x = __float_as_uint(f);
    unsigned int r = x + 0x7fffu + ((x >> 16) & 1u);   // RNE
    return (unsigned short)(r >> 16);
}
static __device__ __forceinline__ float bf2f(unsigned short u) {
    return __uint_as_float(((unsigned int)u) << 16);
}
static __device__ __forceinline__ unsigned pk2(float x, float y) {
    __hip_bfloat162 h = __float22bfloat162_rn(make_float2(x, y));
    return *reinterpret_cast<unsigned*>(&h);
}
static __device__ __forceinline__ short8 cvt8(float4 f0, float4 f1) {
    union { unsigned u[4]; short8 s; } r;
    r.u[0] = pk2(f0.x, f0.y); r.u[1] = pk2(f0.z, f0.w);
    r.u[2] = pk2(f1.x, f1.y); r.u[3] = pk2(f1.z, f1.w);
    return r.s;
}

// ---------------------------------------------------------------------------
// fp32 -> bf16 conversion pass: xq,xk,xv (4M each) + wq,wk,wv,wo (1M each)
// ---------------------------------------------------------------------------
__global__ __launch_bounds__(256) void cvt7(
    const float* __restrict__ s0, const float* __restrict__ s1,
    const float* __restrict__ s2, const float* __restrict__ s3,
    const float* __restrict__ s4, const float* __restrict__ s5,
    const float* __restrict__ s6, unsigned short* __restrict__ dst) {
    const float* s; size_t doff; int n;
    switch (blockIdx.y) {
        case 0: s = s0; doff = 0;                          n = MAT;  break;
        case 1: s = s1; doff = (size_t)MAT;                n = MAT;  break;
        case 2: s = s2; doff = (size_t)2 * MAT;            n = MAT;  break;
        case 3: s = s3; doff = (size_t)3 * MAT;            n = WMAT; break;
        case 4: s = s4; doff = (size_t)3 * MAT + WMAT;     n = WMAT; break;
        case 5: s = s5; doff = (size_t)3 * MAT + 2 * WMAT; n = WMAT; break;
        default: s = s6; doff = (size_t)3 * MAT + 3 * WMAT; n = WMAT; break;
    }
    int idx = (blockIdx.x * 256 + threadIdx.x) * 8;
    if (idx >= n) return;
    float4 a = *(const float4*)(s + idx);
    float4 b = *(const float4*)(s + idx + 4);
    *(short8*)&dst[doff + idx] = cvt8(a, b);
}

// ---------------------------------------------------------------------------
// 128x128 NT GEMM, bf16 operands: out[m,n] = sum_k X[m,k]*W[n,k] + bias
// ROWBIAS: bias indexed by m (for transposed-output GEMMs). OSTRIDE: out row
// stride in elements.
// ---------------------------------------------------------------------------
template <bool F32OUT, bool ROWBIAS, int OSTRIDE>
static __device__ __forceinline__ void gemm_bb(const unsigned short* __restrict__ X,
                                               const unsigned short* __restrict__ W,
                                               const float* __restrict__ bias,
                                               void* __restrict__ outp) {
    __shared__ __align__(16) unsigned short Asm[128 * 72];
    __shared__ __align__(16) unsigned short Bsm[128 * 72];

    const int tid = threadIdx.x;
    const int lane = tid & 63;
    const int wv = tid >> 6;
    const int g = lane >> 4;
    const int lm = lane & 15;
    const int wr = wv >> 1;
    const int wc = wv & 1;
    const int m0 = blockIdx.y * 128;
    const int n0 = blockIdx.x * 128;

    floatx4 acc[4][4];
#pragma unroll
    for (int mi = 0; mi < 4; ++mi)
#pragma unroll
        for (int ni = 0; ni < 4; ++ni)
            acc[mi][ni] = (floatx4){0.f, 0.f, 0.f, 0.f};

    for (int k0 = 0; k0 < 1024; k0 += 64) {
#pragma unroll
        for (int i = 0; i < 4; ++i) {
            int idx = tid + i * 256;
            int row = idx >> 3;
            int col = (idx & 7) << 3;
            *(uint4*)&Asm[row * 72 + col] =
                *(const uint4*)&X[(size_t)(m0 + row) * 1024 + k0 + col];
            *(uint4*)&Bsm[row * 72 + col] =
                *(const uint4*)&W[(size_t)(n0 + row) * 1024 + k0 + col];
        }
        __syncthreads();
#pragma unroll
        for (int ks = 0; ks < 64; ks += 32) {
            short8 af[4], bfr[4];
#pragma unroll
            for (int mi = 0; mi < 4; ++mi)
                af[mi] = *(const short8*)&Asm[(wr * 64 + mi * 16 + lm) * 72 + ks + g * 8];
#pragma unroll
            for (int ni = 0; ni < 4; ++ni)
                bfr[ni] = *(const short8*)&Bsm[(wc * 64 + ni * 16 + lm) * 72 + ks + g * 8];
#pragma unroll
            for (int mi = 0; mi < 4; ++mi)
#pragma unroll
                for (int ni = 0; ni < 4; ++ni)
                    acc[mi][ni] = __builtin_amdgcn_mfma_f32_16x16x32_bf16(
                        af[mi], bfr[ni], acc[mi][ni], 0, 0, 0);
        }
        __syncthreads();
    }

    float cb[4];
#pragma unroll
    for (int ni = 0; ni < 4; ++ni)
        cb[ni] = ROWBIAS ? 0.f : bias[n0 + wc * 64 + ni * 16 + lm];
#pragma unroll
    for (int mi = 0; mi < 4; ++mi)
#pragma unroll
        for (int r = 0; r < 4; ++r) {
            int rowg = m0 + wr * 64 + mi * 16 + g * 4 + r;
            float rb = ROWBIAS ? bias[rowg] : 0.f;
#pragma unroll
            for (int ni = 0; ni < 4; ++ni) {
                int colg = n0 + wc * 64 + ni * 16 + lm;
                float val = acc[mi][ni][r] + (ROWBIAS ? rb : cb[ni]);
                if (F32OUT)
                    ((float*)outp)[(size_t)rowg * OSTRIDE + colg] = val;
                else
                    ((unsigned short*)outp)[(size_t)rowg * OSTRIDE + colg] = f2bf(val);
            }
        }
}

__global__ __launch_bounds__(256) void qkv_gemm_b(
    const unsigned short* __restrict__ Xb, const unsigned short* __restrict__ Wb,
    const float* __restrict__ bq, const float* __restrict__ bk,
    unsigned short* __restrict__ QK) {
    const int z = blockIdx.z;                    // 0 = Q, 1 = K
    const float* bias = (z == 0) ? bq : bk;
    gemm_bb<false, false, 1024>(Xb + (size_t)z * MAT, Wb + (size_t)z * WMAT, bias,
                                QK + (size_t)z * MAT);
}

// V^T projection: out[m=feature][n=token] = sum_k Wv[m,k]*Xv[n,k] + bv[m]
__global__ __launch_bounds__(256) void vt_gemm_b(
    const unsigned short* __restrict__ Wv, const unsigned short* __restrict__ Xv,
    const float* __restrict__ bv, unsigned short* __restrict__ VT) {
    gemm_bb<false, true, 4096>(Wv, Xv, bv, VT);
}

__global__ __launch_bounds__(256) void out_gemm_b(
    const unsigned short* __restrict__ ctx, const unsigned short* __restrict__ Wo,
    const float* __restrict__ bo, float* __restrict__ out) {
    gemm_bb<true, false, 1024>(ctx, Wo, bo, out);
}

// ---------------- fallback path (fp32 staging), used if ws too small --------
template <bool ROWBIAS, int OSTRIDE>
static __device__ __forceinline__ void gemm128_f(const float* __restrict__ X,
                                                 const float* __restrict__ W,
                                                 const float* __restrict__ bias,
                                                 unsigned short* __restrict__ out) {
    __shared__ __align__(16) unsigned short Asm[128 * 72];
    __shared__ __align__(16) unsigned short Bsm[128 * 72];
    const int tid = threadIdx.x;
    const int lane = tid & 63;
    const int wv = tid >> 6;
    const int g = lane >> 4;
    const int lm = lane & 15;
    const int wr = wv >> 1;
    const int wc = wv & 1;
    const int m0 = blockIdx.y * 128;
    const int n0 = blockIdx.x * 128;
    floatx4 acc[4][4];
#pragma unroll
    for (int mi = 0; mi < 4; ++mi)
#pragma unroll
        for (int ni = 0; ni < 4; ++ni)
            acc[mi][ni] = (floatx4){0.f, 0.f, 0.f, 0.f};
    for (int k0 = 0; k0 < 1024; k0 += 64) {
#pragma unroll
        for (int i = 0; i < 4; ++i) {
            int idx = tid + i * 256;
            int row = idx >> 3;
            int col = (idx & 7) << 3;
            const float* sa = &X[(size_t)(m0 + row) * 1024 + k0 + col];
            *(short8*)&Asm[row * 72 + col] = cvt8(*(const float4*)sa, *(const float4*)(sa + 4));
            const float* sb = &W[(size_t)(n0 + row) * 1024 + k0 + col];
            *(short8*)&Bsm[row * 72 + col] = cvt8(*(const float4*)sb, *(const float4*)(sb + 4));
        }
        __syncthreads();
#pragma unroll
        for (int ks = 0; ks < 64; ks += 32) {
            short8 af[4], bfr[4];
#pragma unroll
            for (int mi = 0; mi < 4; ++mi)
                af[mi] = *(const short8*)&Asm[(wr * 64 + mi * 16 + lm) * 72 + ks + g * 8];
#pragma unroll
            for (int ni = 0; ni < 4; ++ni)
                bfr[ni] = *(const short8*)&Bsm[(wc * 64 + ni * 16 + lm) * 72 + ks + g * 8];
#pragma unroll
            for (int mi = 0; mi < 4; ++mi)
#pragma unroll
                for (int ni = 0; ni < 4; ++ni)
                    acc[mi][ni] = __builtin_amdgcn_mfma_f32_16x16x32_bf16(
                        af[mi], bfr[ni], acc[mi][ni], 0, 0, 0);
        }
        __syncthreads();
    }
    float cb[4];
#pragma unroll
    for (int ni = 0; ni < 4; ++ni)
        cb[ni] = ROWBIAS ? 0.f : bias[n0 + wc * 64 + ni * 16 + lm];
#pragma unroll
    for (int mi = 0; mi < 4; ++mi)
#pragma unroll
        for (int r = 0; r < 4; ++r) {
            int rowg = m0 + wr * 64 + mi * 16 + g * 4 + r;
            float rb = ROWBIAS ? bias[rowg] : 0.f;
#pragma unroll
            for (int ni = 0; ni < 4; ++ni) {
                int colg = n0 + wc * 64 + ni * 16 + lm;
                out[(size_t)rowg * OSTRIDE + colg] =
                    f2bf(acc[mi][ni][r] + (ROWBIAS ? rb : cb[ni]));
            }
        }
}

__global__ __launch_bounds__(256) void qkv_gemm_f(
    const float* __restrict__ xq, const float* __restrict__ xk,
    const float* __restrict__ wq, const float* __restrict__ wk,
    const float* __restrict__ bq, const float* __restrict__ bk,
    unsigned short* __restrict__ q, unsigned short* __restrict__ k) {
    if (blockIdx.z == 0) gemm128_f<false, 1024>(xq, wq, bq, q);
    else                 gemm128_f<false, 1024>(xk, wk, bk, k);
}

__global__ __launch_bounds__(256) void vt_gemm_f(
    const float* __restrict__ wv, const float* __restrict__ xv,
    const float* __restrict__ bv, unsigned short* __restrict__ VT) {
    gemm128_f<true, 4096>(wv, xv, bv, VT);
}

__global__ __launch_bounds__(256) void out_gemm_f(
    const float* __restrict__ wo, const float* __restrict__ bo,
    const unsigned short* __restrict__ ctx, float* __restrict__ out) {
    __shared__ __align__(16) unsigned short Asm[128 * 72];
    __shared__ __align__(16) unsigned short Bsm[128 * 72];
    const int tid = threadIdx.x;
    const int lane = tid & 63;
    const int wv = tid >> 6;
    const int g = lane >> 4;
    const int lm = lane & 15;
    const int wr = wv >> 1;
    const int wc = wv & 1;
    const int m0 = blockIdx.y * 128;
    const int n0 = blockIdx.x * 128;
    floatx4 acc[4][4];
#pragma unroll
    for (int mi = 0; mi < 4; ++mi)
#pragma unroll
        for (int ni = 0; ni < 4; ++ni)
            acc[mi][ni] = (floatx4){0.f, 0.f, 0.f, 0.f};
    for (int k0 = 0; k0 < 1024; k0 += 64) {
#pragma unroll
        for (int i = 0; i < 4; ++i) {
            int idx = tid + i * 256;
            int row = idx >> 3;
            int col = (idx & 7) << 3;
            *(uint4*)&Asm[row * 72 + col] =
                *(const uint4*)&ctx[(size_t)(m0 + row) * 1024 + k0 + col];
            const float* sb = &wo[(size_t)(n0 + row) * 1024 + k0 + col];
            *(short8*)&Bsm[row * 72 + col] = cvt8(*(const float4*)sb, *(const float4*)(sb + 4));
        }
        __syncthreads();
#pragma unroll
        for (int ks = 0; ks < 64; ks += 32) {
            short8 af[4], bfr[4];
#pragma unroll
            for (int mi = 0; mi < 4; ++mi)
                af[mi] = *(const short8*)&Asm[(wr * 64 + mi * 16 + lm) * 72 + ks + g * 8];
#pragma unroll
            for (int ni = 0; ni < 4; ++ni)
                bfr[ni] = *(const short8*)&Bsm[(wc * 64 + ni * 16 + lm) * 72 + ks + g * 8];
#pragma unroll
            for (int mi = 0; mi < 4; ++mi)
#pragma unroll
                for (int ni = 0; ni < 4; ++ni)
                    acc[mi][ni] = __builtin_amdgcn_mfma_f32_16x16x32_bf16(
                        af[mi], bfr[ni], acc[mi][ni], 0, 0, 0);
        }
        __syncthreads();
    }
    float bb[4];
#pragma unroll
    for (int ni = 0; ni < 4; ++ni)
        bb[ni] = bo[n0 + wc * 64 + ni * 16 + lm];
#pragma unroll
    for (int mi = 0; mi < 4; ++mi)
#pragma unroll
        for (int ni = 0; ni < 4; ++ni)
#pragma unroll
            for (int r = 0; r < 4; ++r) {
                int rowg = m0 + wr * 64 + mi * 16 + g * 4 + r;
                int colg = n0 + wc * 64 + ni * 16 + lm;
                out[(size_t)rowg * 1024 + colg] = acc[mi][ni][r] + bb[ni];
            }
}

// ---------------------------------------------------------------------------
// Flash attention v5: S^T orientation, P in registers, V pre-transposed.
// r5's stage->sync->compute structure (loads go straight to LDS, nothing
// lives across a barrier => no scratch spill, unlike r7's register prefetch).
//   S^T = mfma(K_frag, Q_frag): C rows = keys kb*16+g*4+r, cols = q lm.
//   PV slot-remap (slot g*8+j <-> key c*16+g*4+(j&3), c=2cp+(j>>2)):
//     A = pk2-packed exp(S^T) from registers, B = Vt via 2x ds_read_b64.
// ---------------------------------------------------------------------------
__global__ __launch_bounds__(256) void attn_kernel(
    const unsigned short* __restrict__ Q, const unsigned short* __restrict__ K,
    const unsigned short* __restrict__ VT, unsigned short* __restrict__ CTX) {
    __shared__ __align__(16) unsigned short Ksm[64 * 72];
    __shared__ __align__(16) unsigned short Vt[64 * 72];

    const int tid = threadIdx.x;
    const int lane = tid & 63;
    const int w = tid >> 6;
    const int g = lane >> 4;
    const int lm = lane & 15;
    const int qt = blockIdx.x;
    const int bh = blockIdx.y;
    const int b = bh >> 4;
    const int h = bh & 15;

    const size_t base = (size_t)b * SEQ * D_MODEL + (size_t)h * DK;
    // VT: [1024 features][4096 tokens]; head h -> rows h*64.., batch b -> cols b*2048..
    const size_t vtbase = (size_t)(h * 64) * NTOK + (size_t)b * SEQ;

    // staging coords (shared by K and Vt tiles)
    const int srow0 = tid >> 3;            // 0..31   (+32 on second iter)
    const int scol = (tid & 7) << 3;       // 0,8,...,56

    // Q fragments (B-operand for S^T), prescaled by 1/8
    short8 qf[2];
    const int qrow = qt * 64 + w * 16 + lm;
#pragma unroll
    for (int t = 0; t < 2; ++t) {
        short8 raw = *(const short8*)&Q[base + (size_t)qrow * D_MODEL + t * 32 + g * 8];
        union { unsigned u[4]; short8 s; } r;
#pragma unroll
        for (int j = 0; j < 4; ++j) {
            float lo = bf2f((unsigned short)raw[2 * j]) * 0.125f;
            float hi = bf2f((unsigned short)raw[2 * j + 1]) * 0.125f;
            r.u[j] = pk2(lo, hi);
        }
        qf[t] = r.s;
    }

    float lsum = 0.f;
    floatx4 Oacc[4];
#pragma unroll
    for (int nb = 0; nb < 4; ++nb) Oacc[nb] = (floatx4){0.f, 0.f, 0.f, 0.f};

    for (int kt = 0; kt < SEQ / 64; ++kt) {
        const int krow0 = kt * 64;
        // ---- stage K and Vt tiles: coalesced uint4 load -> immediate LDS write
#pragma unroll
        for (int i = 0; i < 2; ++i) {
            int row = srow0 + i * 32;
            *(uint4*)&Ksm[row * 72 + scol] =
                *(const uint4*)&K[base + (size_t)(krow0 + row) * D_MODEL + scol];
            *(uint4*)&Vt[row * 72 + scol] =
                *(const uint4*)&VT[vtbase + (size_t)row * NTOK + krow0 + scol];
        }
        __syncthreads();

        // ---- S^T = K Q^T / 8 : per kb, rows = keys kb*16+g*4+r, col q=lm ----
        float p[4][4];
#pragma unroll
        for (int kb = 0; kb < 4; ++kb) {
            floatx4 a = (floatx4){0.f, 0.f, 0.f, 0.f};
#pragma unroll
            for (int t = 0; t < 2; ++t) {
                short8 ak = *(const short8*)&Ksm[(kb * 16 + lm) * 72 + t * 32 + g * 8];
                a = __builtin_amdgcn_mfma_f32_16x16x32_bf16(ak, qf[t], a, 0, 0, 0);
            }
#pragma unroll
            for (int r = 0; r < 4; ++r) p[kb][r] = __expf(a[r]);
            lsum += (p[kb][0] + p[kb][1]) + (p[kb][2] + p[kb][3]);
        }

        // ---- O += P V  (slot g*8+j <-> key c*16+g*4+(j&3), c = 2cp+(j>>2)) ----
#pragma unroll
        for (int cp = 0; cp < 2; ++cp) {
            const int c0 = 2 * cp, c1 = 2 * cp + 1;
            union { unsigned u[4]; short8 s; } ap;
            ap.u[0] = pk2(p[c0][0], p[c0][1]);
            ap.u[1] = pk2(p[c0][2], p[c0][3]);
            ap.u[2] = pk2(p[c1][0], p[c1][1]);
            ap.u[3] = pk2(p[c1][2], p[c1][3]);
#pragma unroll
            for (int nb = 0; nb < 4; ++nb) {
                const int d = nb * 16 + lm;
                uint2 x0 = *(const uint2*)&Vt[d * 72 + c0 * 16 + g * 4];
                uint2 x1 = *(const uint2*)&Vt[d * 72 + c1 * 16 + g * 4];
                union { unsigned u[4]; short8 s; } bv;
                bv.u[0] = x0.x; bv.u[1] = x0.y; bv.u[2] = x1.x; bv.u[3] = x1.y;
                Oacc[nb] = __builtin_amdgcn_mfma_f32_16x16x32_bf16(
                    ap.s, bv.s, Oacc[nb], 0, 0, 0);
            }
        }
        __syncthreads();
    }

    // ---- softmax denominator: reduce over g, redistribute to rows ----
    lsum += __shfl_xor(lsum, 16, 64);
    lsum += __shfl_xor(lsum, 32, 64);   // all lanes: full l for q = w*16+lm
    float lr[4];
#pragma unroll
    for (int r = 0; r < 4; ++r)
        lr[r] = __shfl(lsum, g * 4 + r, 64);   // l for q-row = w*16+g*4+r

#pragma unroll
    for (int nb = 0; nb < 4; ++nb) {
#pragma unroll
        for (int r = 0; r < 4; ++r) {
            float val = Oacc[nb][r] / lr[r];
            int srow = qt * 64 + w * 16 + g * 4 + r;
            CTX[base + (size_t)srow * D_MODEL + nb * 16 + lm] = f2bf(val);
        }
    }
}

extern "C" void kernel_launch(void* const* d_in, const int* in_sizes, int n_in,
                              void* d_out, int out_size, void* d_ws, size_t ws_size,
                              hipStream_t stream) {
    const float* xq = (const float*)d_in[0];
    const float* xk = (const float*)d_in[1];
    const float* xv = (const float*)d_in[2];
    const float* wq = (const float*)d_in[3];
    const float* bq = (const float*)d_in[4];
    const float* wk = (const float*)d_in[5];
    const float* bk = (const float*)d_in[6];
    const float* wv = (const float*)d_in[7];
    const float* bv = (const float*)d_in[8];
    const float* wo = (const float*)d_in[9];
    const float* bo = (const float*)d_in[10];
    float* out = (float*)d_out;

    unsigned short* ws = (unsigned short*)d_ws;

    if (ws_size >= (size_t)68 * 1024 * 1024) {
        // bf16 path: Xb[3*MAT] | Wb[4*WMAT] | Q | K | VT | C
        unsigned short* Xb = ws;
        unsigned short* Wb = ws + (size_t)3 * MAT;
        unsigned short* Qw = Wb + (size_t)4 * WMAT;
        unsigned short* Kw = Qw + (size_t)MAT;
        unsigned short* VTw = Kw + (size_t)MAT;
        unsigned short* Cw = VTw + (size_t)MAT;

        cvt7<<<dim3(2048, 7), 256, 0, stream>>>(xq, xk, xv, wq, wk, wv, wo, ws);
        qkv_gemm_b<<<dim3(8, 32, 2), 256, 0, stream>>>(Xb, Wb, bq, bk, Qw);
        vt_gemm_b<<<dim3(32, 8), 256, 0, stream>>>(
            Wb + (size_t)2 * WMAT, Xb + (size_t)2 * MAT, bv, VTw);
        attn_kernel<<<dim3(SEQ / 64, 2 * NH), 256, 0, stream>>>(Qw, Kw, VTw, Cw);
        out_gemm_b<<<dim3(8, 32), 256, 0, stream>>>(Cw, Wb + (size_t)3 * WMAT, bo, out);
    } else {
        unsigned short* Qw = ws;
        unsigned short* Kw = ws + (size_t)MAT;
        unsigned short* VTw = ws + (size_t)2 * MAT;
        unsigned short* Cw = ws + (size_t)3 * MAT;
        qkv_gemm_f<<<dim3(8, 32, 2), 256, 0, stream>>>(xq, xk, wq, wk, bq, bk, Qw, Kw);
        vt_gemm_f<<<dim3(32, 8), 256, 0, stream>>>(wv, xv, bv, VTw);
        attn_kernel<<<dim3(SEQ / 64, 2 * NH), 256, 0, stream>>>(Qw, Kw, VTw, Cw);
        out_gemm_f<<<dim3(8, 32), 256, 0, stream>>>(wo, bo, Cw, out);
    }
}